// Round 7
// baseline (185.700 us; speedup 1.0000x reference)
//
#include <hip/hip_runtime.h>
#include <hip/hip_bf16.h>

#define SEQ 2048
#define BATCH 4
#define HID 1024

typedef __bf16 bf16x8 __attribute__((ext_vector_type(8)));
typedef __bf16 bf16x4 __attribute__((ext_vector_type(4)));
typedef float f32x4 __attribute__((ext_vector_type(4)));

__device__ __forceinline__ void gload_lds16(void* lds, const void* g) {
  __builtin_amdgcn_global_load_lds(
      (const __attribute__((address_space(1))) void*)g,
      (__attribute__((address_space(3))) void*)lds, 16, 0, 0);
}

// ---------------- casts ----------------
__global__ __launch_bounds__(256) void cast_f32_bf16(const float* __restrict__ in,
                                                     __bf16* __restrict__ out, int n8) {
  int i = blockIdx.x * 256 + threadIdx.x;
  if (i >= n8) return;
  const float4* p = (const float4*)in + (size_t)i * 2;
  float4 a = p[0], b = p[1];
  bf16x8 v;
  v[0] = (__bf16)a.x; v[1] = (__bf16)a.y; v[2] = (__bf16)a.z; v[3] = (__bf16)a.w;
  v[4] = (__bf16)b.x; v[5] = (__bf16)b.y; v[6] = (__bf16)b.z; v[7] = (__bf16)b.w;
  ((bf16x8*)out)[i] = v;
}

__global__ __launch_bounds__(256) void cast_w3(const float* __restrict__ w0,
                                               const float* __restrict__ w1,
                                               const float* __restrict__ w2,
                                               __bf16* __restrict__ out) {
  const int wsel = blockIdx.y;
  const float* src = wsel == 0 ? w0 : wsel == 1 ? w1 : w2;
  int i = blockIdx.x * 256 + threadIdx.x;
  const float4* p = (const float4*)src + (size_t)i * 2;
  float4 a = p[0], b = p[1];
  bf16x8 v;
  v[0] = (__bf16)a.x; v[1] = (__bf16)a.y; v[2] = (__bf16)a.z; v[3] = (__bf16)a.w;
  v[4] = (__bf16)b.x; v[5] = (__bf16)b.y; v[6] = (__bf16)b.z; v[7] = (__bf16)b.w;
  ((bf16x8*)(out + (size_t)wsel * HID * HID))[i] = v;
}

__global__ void concat_bias(const float* b0, const float* b1, const float* b2,
                            float* __restrict__ out) {
  const float* s = blockIdx.x == 0 ? b0 : blockIdx.x == 1 ? b1 : b2;
  out[blockIdx.x * HID + threadIdx.x] = s[threadIdx.x];
}

// ======= 3-phase 256x256xBK64 B^T GEMM, dbuf-2, unit-staggered counted vmcnt =======
// 8 waves (2M x 4N), wave tile 128x64 with INTERLEAVED sub-tiles:
//   m-rows: {wr*64..+63} u {128+wr*64..+63};  n-cols: {wc*32..+31} u {128+wc*32..+31}
// Staging units per K-tile: U0={A0-127,B0-127}(4 loads) U1={B128-255}(2) U2={A128-255}(2)
// consumed at ph0/ph1/ph2; issued 3 units ahead -> waits vmcnt(4)/(6)/(6), never 0.
// EPI 0: QKV (M flat 8192, rows s*4+b); EPI 2: exp-scores + row partials.
template<int EPI>
__global__ __launch_bounds__(512, 2)
void gemm3p(const __bf16* __restrict__ A, int lda, long long sAz,
            const __bf16* __restrict__ B, int ldb, long long sBz,
            const float* __restrict__ aux, void* __restrict__ dst,
            float* __restrict__ aux2, int K)
{
  __shared__ __align__(16) char lds[2 * 65536];   // per buf: A 32KB | B 32KB
  const int tid = threadIdx.x;
  const int wid = tid >> 6, lane = tid & 63;
  const int wr = wid >> 2, wc = wid & 3;
  const int m0 = blockIdx.x * 256, n0 = blockIdx.y * 256;
  const int z = blockIdx.z;
  const __bf16* Ab = A + (size_t)z * sAz;
  const __bf16* Bb = B + (size_t)z * sBz;

  const int srow = tid >> 3;
  const int scol = ((tid & 7) * 16) ^ ((srow & 7) << 4);
  const char* a0s = (const char*)(Ab + (size_t)(m0 + srow) * lda) + scol;
  const char* a1s = (const char*)(Ab + (size_t)(m0 + 64 + srow) * lda) + scol;
  const char* a2s = (const char*)(Ab + (size_t)(m0 + 128 + srow) * lda) + scol;
  const char* a3s = (const char*)(Ab + (size_t)(m0 + 192 + srow) * lda) + scol;
  const char* b0s = (const char*)(Bb + (size_t)(n0 + srow) * ldb) + scol;
  const char* b1s = (const char*)(Bb + (size_t)(n0 + 64 + srow) * ldb) + scol;
  const char* b2s = (const char*)(Bb + (size_t)(n0 + 128 + srow) * ldb) + scol;
  const char* b3s = (const char*)(Bb + (size_t)(n0 + 192 + srow) * ldb) + scol;
  const int dT = tid * 16;

  auto U0 = [&](char* sb, size_t ko) {
    gload_lds16(sb + dT, a0s + ko);
    gload_lds16(sb + 8192 + dT, a1s + ko);
    gload_lds16(sb + 32768 + dT, b0s + ko);
    gload_lds16(sb + 40960 + dT, b1s + ko);
  };
  auto U1 = [&](char* sb, size_t ko) {
    gload_lds16(sb + 49152 + dT, b2s + ko);
    gload_lds16(sb + 57344 + dT, b3s + ko);
  };
  auto U2 = [&](char* sb, size_t ko) {
    gload_lds16(sb + 16384 + dT, a2s + ko);
    gload_lds16(sb + 24576 + dT, a3s + ko);
  };

  const int fr = lane & 15, fq = lane >> 4;
  const int swz = (fr & 7) << 4;
  const int c0 = (fq * 16) ^ swz;           // ks term: c(ks) = c0 ^ (ks<<6)
  const int arow = (wr * 64 + fr) * 128;              // + mi*2048 (+16384 for hi half)
  const int brow = 32768 + (wc * 32 + fr) * 128;      // + ni*2048 (+16384 for hi half)

  const int nk = K >> 6;
  U0(lds, 0); U1(lds, 0); U2(lds, 0);

  f32x4 acc[8][4] = {};
  for (int t = 0; t < nk; ++t) {
    char* sb = lds + (t & 1) * 65536;
    char* sn = lds + ((t + 1) & 1) * 65536;
    const size_t ko = (size_t)(t + 1) * 128;
    const bool more = (t + 1 < nk);

    bf16x8 a[4][2], b0[2][2], b1[2][2];
    // ---- phase 0: U0(t) ready; read a-lo + b-lo; issue U0(t+1); MFMA lo x lo ----
    asm volatile("s_waitcnt vmcnt(4)" ::: "memory");
    __builtin_amdgcn_s_barrier();
    asm volatile("" ::: "memory");
#pragma unroll
    for (int mi = 0; mi < 4; ++mi)
#pragma unroll
      for (int ks = 0; ks < 2; ++ks)
        a[mi][ks] = *(const bf16x8*)(sb + arow + mi * 2048 + (c0 ^ (ks << 6)));
#pragma unroll
    for (int ni = 0; ni < 2; ++ni)
#pragma unroll
      for (int ks = 0; ks < 2; ++ks)
        b0[ni][ks] = *(const bf16x8*)(sb + brow + ni * 2048 + (c0 ^ (ks << 6)));
    if (more) U0(sn, ko);
    asm volatile("s_waitcnt lgkmcnt(0)" ::: "memory");
    __builtin_amdgcn_sched_barrier(0);
    __builtin_amdgcn_s_setprio(1);
#pragma unroll
    for (int mi = 0; mi < 4; ++mi)
#pragma unroll
      for (int ni = 0; ni < 2; ++ni)
#pragma unroll
        for (int ks = 0; ks < 2; ++ks)
          acc[mi][ni] = __builtin_amdgcn_mfma_f32_16x16x32_bf16(a[mi][ks], b0[ni][ks], acc[mi][ni], 0, 0, 0);
    __builtin_amdgcn_s_setprio(0);

    // ---- phase 1: U1(t) ready; read b-hi; issue U1(t+1); MFMA lo x hi ----
    if (more) asm volatile("s_waitcnt vmcnt(6)" ::: "memory");
    else      asm volatile("s_waitcnt vmcnt(2)" ::: "memory");
    __builtin_amdgcn_s_barrier();
    asm volatile("" ::: "memory");
#pragma unroll
    for (int ni = 0; ni < 2; ++ni)
#pragma unroll
      for (int ks = 0; ks < 2; ++ks)
        b1[ni][ks] = *(const bf16x8*)(sb + brow + 16384 + ni * 2048 + (c0 ^ (ks << 6)));
    if (more) U1(sn, ko);
    asm volatile("s_waitcnt lgkmcnt(0)" ::: "memory");
    __builtin_amdgcn_sched_barrier(0);
    __builtin_amdgcn_s_setprio(1);
#pragma unroll
    for (int mi = 0; mi < 4; ++mi)
#pragma unroll
      for (int ni = 0; ni < 2; ++ni)
#pragma unroll
        for (int ks = 0; ks < 2; ++ks)
          acc[mi][2 + ni] = __builtin_amdgcn_mfma_f32_16x16x32_bf16(a[mi][ks], b1[ni][ks], acc[mi][2 + ni], 0, 0, 0);
    __builtin_amdgcn_s_setprio(0);

    // ---- phase 2: U2(t) ready; read a-hi (reuse regs); issue U2(t+1); MFMA hi x all ----
    if (more) asm volatile("s_waitcnt vmcnt(6)" ::: "memory");
    else      asm volatile("s_waitcnt vmcnt(0)" ::: "memory");
    __builtin_amdgcn_s_barrier();
    asm volatile("" ::: "memory");
#pragma unroll
    for (int mi = 0; mi < 4; ++mi)
#pragma unroll
      for (int ks = 0; ks < 2; ++ks)
        a[mi][ks] = *(const bf16x8*)(sb + arow + 16384 + mi * 2048 + (c0 ^ (ks << 6)));
    if (more) U2(sn, ko);
    asm volatile("s_waitcnt lgkmcnt(0)" ::: "memory");
    __builtin_amdgcn_sched_barrier(0);
    __builtin_amdgcn_s_setprio(1);
#pragma unroll
    for (int mi = 0; mi < 4; ++mi)
#pragma unroll
      for (int ks = 0; ks < 2; ++ks) {
#pragma unroll
        for (int ni = 0; ni < 2; ++ni)
          acc[4 + mi][ni] = __builtin_amdgcn_mfma_f32_16x16x32_bf16(a[mi][ks], b0[ni][ks], acc[4 + mi][ni], 0, 0, 0);
#pragma unroll
        for (int ni = 0; ni < 2; ++ni)
          acc[4 + mi][2 + ni] = __builtin_amdgcn_mfma_f32_16x16x32_bf16(a[mi][ks], b1[ni][ks], acc[4 + mi][2 + ni], 0, 0, 0);
      }
    __builtin_amdgcn_s_setprio(0);
  }
  asm volatile("s_waitcnt vmcnt(0)" ::: "memory");
  __syncthreads();

  // ---- epilogues; D frag row=(lane>>4)*4+r, col=lane&15; interleaved sub-tiles ----
  if (EPI == 0) {
    const size_t BSH = (size_t)BATCH * SEQ * HID;
#pragma unroll
    for (int mi = 0; mi < 8; ++mi) {
      const int rbase = (mi < 4 ? wr * 64 + mi * 16 : 128 + wr * 64 + (mi - 4) * 16) + fq * 4;
#pragma unroll
      for (int ni = 0; ni < 4; ++ni) {
        const int gn = n0 + (ni < 2 ? wc * 32 + ni * 16 : 128 + wc * 32 + (ni - 2) * 16) + fr;
        const int hsel = gn >> 10, h = gn & (HID - 1);
        const float bias = aux[gn];
        f32x4 v = acc[mi][ni];
#pragma unroll
        for (int r = 0; r < 4; ++r) {
          const int gm = m0 + rbase + r;           // flat row = s*BATCH+b
          const int b = gm & 3, s = gm >> 2;
          if (hsel < 2)
            ((__bf16*)dst)[(size_t)hsel * BSH + (size_t)b * SEQ * HID +
                           (size_t)s * HID + h] = (__bf16)(v[r] + bias);
          else
            ((__bf16*)dst)[2 * BSH + (size_t)b * HID * SEQ +
                           (size_t)h * SEQ + s] = (__bf16)(v[r] + bias);
        }
      }
    }
  } else {  // EPI == 2
    float psum[8][4] = {};
#pragma unroll
    for (int mi = 0; mi < 8; ++mi) {
      const int rbase = (mi < 4 ? wr * 64 + mi * 16 : 128 + wr * 64 + (mi - 4) * 16) + fq * 4;
#pragma unroll
      for (int ni = 0; ni < 4; ++ni) {
        const int gn = n0 + (ni < 2 ? wc * 32 + ni * 16 : 128 + wc * 32 + (ni - 2) * 16) + fr;
        f32x4 v = acc[mi][ni];
#pragma unroll
        for (int r = 0; r < 4; ++r) {
          const size_t idx = (size_t)z * SEQ * SEQ + (size_t)(m0 + rbase + r) * SEQ + gn;
          const float e = __expf(v[r] * 0.03125f * aux[idx]);
          ((__bf16*)dst)[idx] = (__bf16)e;
          psum[mi][r] += e;
        }
      }
    }
#pragma unroll
    for (int mi = 0; mi < 8; ++mi)
#pragma unroll
      for (int r = 0; r < 4; ++r) {
        float sv = psum[mi][r];
        sv += __shfl_xor(sv, 1); sv += __shfl_xor(sv, 2);
        sv += __shfl_xor(sv, 4); sv += __shfl_xor(sv, 8);
        psum[mi][r] = sv;
      }
    float* red = (float*)lds;   // [4 wc][256 rows]
    if (fr == 0) {
#pragma unroll
      for (int mi = 0; mi < 8; ++mi) {
        const int rbase = (mi < 4 ? wr * 64 + mi * 16 : 128 + wr * 64 + (mi - 4) * 16) + fq * 4;
#pragma unroll
        for (int r = 0; r < 4; ++r)
          red[wc * 256 + rbase + r] = psum[mi][r];
      }
    }
    __syncthreads();
    if (tid < 256) {
      float sv = 0.f;
#pragma unroll
      for (int w = 0; w < 4; ++w) sv += red[w * 256 + tid];
      aux2[((size_t)z * SEQ + m0 + tid) * 8 + blockIdx.y] = sv;
    }
  }
}

// ============ R6 8-wave 128x256xK ring-3 kernel (kept for PV, EPI 3) ============
#define SLOT 49152
template<int EPI>
__global__ __launch_bounds__(512, 2)
void gemm8(const __bf16* __restrict__ A, int lda, long long sAz,
           const __bf16* __restrict__ B, int ldb, long long sBz,
           const float* __restrict__ aux, void* __restrict__ dst,
           float* __restrict__ aux2, int K)
{
  __shared__ __align__(16) char lds[3 * SLOT];
  const int tid = threadIdx.x;
  const int wid = tid >> 6, lane = tid & 63;
  const int wr = wid >> 2, wc = wid & 3;
  const int m0 = blockIdx.x * 128, n0 = blockIdx.y * 256;
  const int z = blockIdx.z;
  const __bf16* Ab = A + (size_t)z * sAz;
  const __bf16* Bb = B + (size_t)z * sBz;

  const int srow = tid >> 3;
  const int scol = ((tid & 7) * 16) ^ ((srow & 7) << 4);
  const char* asrc0 = (const char*)(Ab + (size_t)(m0 + srow) * lda) + scol;
  const char* asrc1 = (const char*)(Ab + (size_t)(m0 + srow + 64) * lda) + scol;
  const char* bsrc0 = (const char*)(Bb + (size_t)(n0 + srow) * ldb) + scol;
  const char* bsrc1 = (const char*)(Bb + (size_t)(n0 + srow + 64) * ldb) + scol;
  const char* bsrc2 = (const char*)(Bb + (size_t)(n0 + srow + 128) * ldb) + scol;
  const char* bsrc3 = (const char*)(Bb + (size_t)(n0 + srow + 192) * ldb) + scol;
  const int dA = tid * 16, dB = 16384 + tid * 16;

  const int fr = lane & 15, fq = lane >> 4;
  const int fc2 = fq * 16;
  const int swz = (fr & 7) << 4;
  int aoff[4][2], boff[4][2];
#pragma unroll
  for (int mi = 0; mi < 4; ++mi) {
    const int row = wr * 64 + mi * 16 + fr;
#pragma unroll
    for (int ks = 0; ks < 2; ++ks)
      aoff[mi][ks] = row * 128 + ((fc2 + ks * 64) ^ swz);
  }
#pragma unroll
  for (int ni = 0; ni < 4; ++ni) {
    const int row = wc * 64 + ni * 16 + fr;
#pragma unroll
    for (int ks = 0; ks < 2; ++ks)
      boff[ni][ks] = 16384 + row * 128 + ((fc2 + ks * 64) ^ swz);
  }

  const int nk = K >> 6;
  {
    char* s0 = lds;
    gload_lds16(s0 + dA, asrc0); gload_lds16(s0 + dA + 8192, asrc1);
    gload_lds16(s0 + dB, bsrc0); gload_lds16(s0 + dB + 8192, bsrc1);
    gload_lds16(s0 + dB + 16384, bsrc2); gload_lds16(s0 + dB + 24576, bsrc3);
    char* s1 = lds + SLOT;
    gload_lds16(s1 + dA, asrc0 + 128); gload_lds16(s1 + dA + 8192, asrc1 + 128);
    gload_lds16(s1 + dB, bsrc0 + 128); gload_lds16(s1 + dB + 8192, bsrc1 + 128);
    gload_lds16(s1 + dB + 16384, bsrc2 + 128); gload_lds16(s1 + dB + 24576, bsrc3 + 128);
  }

  f32x4 acc[4][4] = {};
  for (int t = 0; t < nk; ++t) {
    char* s = lds + (t % 3) * SLOT;
    if (t + 1 < nk) asm volatile("s_waitcnt vmcnt(6)" ::: "memory");
    else            asm volatile("s_waitcnt vmcnt(0)" ::: "memory");
    __builtin_amdgcn_s_barrier();
    asm volatile("" ::: "memory");

    bf16x8 a[4][2], b[4][2];
#pragma unroll
    for (int mi = 0; mi < 4; ++mi)
#pragma unroll
      for (int ks = 0; ks < 2; ++ks)
        a[mi][ks] = *(const bf16x8*)(s + aoff[mi][ks]);
#pragma unroll
    for (int ni = 0; ni < 4; ++ni)
#pragma unroll
      for (int ks = 0; ks < 2; ++ks)
        b[ni][ks] = *(const bf16x8*)(s + boff[ni][ks]);

    if (t + 2 < nk) {
      char* sn = lds + ((t + 2) % 3) * SLOT;
      const size_t ko = (size_t)(t + 2) * 128;
      gload_lds16(sn + dA, asrc0 + ko);
      gload_lds16(sn + dA + 8192, asrc1 + ko);
      gload_lds16(sn + dB, bsrc0 + ko);
      gload_lds16(sn + dB + 8192, bsrc1 + ko);
      gload_lds16(sn + dB + 16384, bsrc2 + ko);
      gload_lds16(sn + dB + 24576, bsrc3 + ko);
    }

    __builtin_amdgcn_s_setprio(1);
#pragma unroll
    for (int mi = 0; mi < 4; ++mi)
#pragma unroll
      for (int ni = 0; ni < 4; ++ni)
#pragma unroll
        for (int ks = 0; ks < 2; ++ks)
          acc[mi][ni] = __builtin_amdgcn_mfma_f32_16x16x32_bf16(a[mi][ks], b[ni][ks], acc[mi][ni], 0, 0, 0);
    __builtin_amdgcn_s_setprio(0);
  }
  __syncthreads();

  if (EPI == 3) {
    float* red = (float*)lds;
    if (tid < 128) {
      const float* pp = aux + ((size_t)z * SEQ + m0 + tid) * 8;
      float sv = 0.f;
#pragma unroll
      for (int j = 0; j < 8; ++j) sv += pp[j];
      red[tid] = 1.f / sv;
    }
    __syncthreads();
#pragma unroll
    for (int mi = 0; mi < 4; ++mi) {
#pragma unroll
      for (int ni = 0; ni < 4; ++ni) {
        const int gn = n0 + wc * 64 + ni * 16 + fr;
        const int rbase = wr * 64 + mi * 16 + fq * 4;
        f32x4 v = acc[mi][ni];
#pragma unroll
        for (int r = 0; r < 4; ++r)
          ((float*)dst)[((size_t)(m0 + rbase + r) * BATCH + z) * HID + gn] = v[r] * red[rbase + r];
      }
    }
  }
}

extern "C" void kernel_launch(void* const* d_in, const int* in_sizes, int n_in,
                              void* d_out, int out_size, void* d_ws, size_t ws_size,
                              hipStream_t stream) {
  const float* x   = (const float*)d_in[0];
  const float* ssm = (const float*)d_in[1];
  const float* Wq  = (const float*)d_in[2];
  const float* bq  = (const float*)d_in[3];
  const float* Wk  = (const float*)d_in[4];
  const float* bk  = (const float*)d_in[5];
  const float* Wv  = (const float*)d_in[6];
  const float* bv  = (const float*)d_in[7];
  float* out = (float*)d_out;

  const size_t BSH = (size_t)BATCH * SEQ * HID;
  float* bqkv    = (float*)d_ws;
  float* partial = bqkv + 4096;
  __bf16* xbf  = (__bf16*)(partial + (size_t)BATCH * SEQ * 8);
  __bf16* wqkv = xbf + BSH;
  __bf16* Qb = wqkv + (size_t)3 * HID * HID;   // Q | K | Vt
  __bf16* Kb = Qb + BSH;
  __bf16* Vt = Qb + 2 * BSH;
  __bf16* E  = Qb + 3 * BSH;

  cast_f32_bf16<<<(int)(BSH / 8 / 256), 256, 0, stream>>>(x, xbf, (int)(BSH / 8));
  cast_w3<<<dim3(HID * HID / 8 / 256, 3), 256, 0, stream>>>(Wq, Wk, Wv, wqkv);
  concat_bias<<<3, HID, 0, stream>>>(bq, bk, bv, bqkv);

  // QKV: M = 8192 flat rows (s*4+b), N = 3072, K = 1024
  gemm3p<0><<<dim3(32, 12, 1), 512, 0, stream>>>(xbf, HID, 0,
                                                 wqkv, HID, 0, bqkv, Qb, nullptr, HID);
  // scores: per z, 2048 x 2048 x 1024
  gemm3p<2><<<dim3(8, 8, 4), 512, 0, stream>>>(Qb, HID, (long long)SEQ * HID,
                                               Kb, HID, (long long)SEQ * HID,
                                               ssm, E, partial, HID);
  // PV: per z, 2048 x 1024 x 2048 (R6 ring-3 kernel)
  gemm8<3><<<dim3(16, 4, 4), 512, 0, stream>>>(E, SEQ, (long long)SEQ * SEQ,
                                               Vt, SEQ, (long long)HID * SEQ,
                                               partial, out, nullptr, SEQ);
}